// Round 10
// baseline (1393.723 us; speedup 1.0000x reference)
//
#include <hip/hip_runtime.h>

typedef unsigned short u16;
typedef unsigned int   u32;
typedef unsigned char  u8;
typedef unsigned long long u64;
typedef long i64;
typedef __attribute__((ext_vector_type(8))) short s16x8;
typedef __attribute__((ext_vector_type(4))) float f32x4;
typedef __attribute__((ext_vector_type(2))) float f32x2;
typedef __attribute__((ext_vector_type(4), aligned(4))) float f32x4u;

#define DEV static __device__ __forceinline__

constexpr int B_ = 512, T_ = 200, V_ = 99, H_ = 256;
constexpr int TV_ = T_ * V_;
constexpr u32 BH_ = B_ * H_;

// d_out f32 element offsets: (x_imp, y_out, y_score, x_loss, xus, xrs)
constexpr long long XIMP_O = 0;
constexpr long long YOUT_O = 10137600;
constexpr long long YSC_O  = 10138112;
constexpr long long LOSS_O = 10138624;
constexpr long long XUS_O  = 10138625;
constexpr long long XRS_O  = 20276225;

// ---- workspace byte offsets ----
constexpr long long WS_MSUM   = 0;                          // 200 f32
constexpr long long WS_GAMMA  = 1024;                       // [T][B][H] bf16
constexpr long long WS_XRPRE  = 52429824;                   // [T][B][99] bf16
constexpr long long WS_X16    = 72705024;                   // [T][B][100] bf16
constexpr long long WS_XUS16  = 93185024;                   // [T][B][99] bf16
constexpr long long WS_M8     = 113460224;                  // [T][B][104] u8
constexpr long long WS_GIM8   = 124109824;                  // [T][32][48][64][4] u8 (78,643,200)
constexpr long long WS_WTD    = 202753024;                  // bf16 packs (k2)
constexpr long long WS_WU     = WS_WTD + 65536;
constexpr long long WS_WV     = WS_WU + 28672;
constexpr long long WS_WRB    = WS_WV + 28672;
constexpr long long WS_F8     = WS_WRB + 28672;             // fp8 packs
constexpr long long WS_WIHX8  = WS_F8;                      // 96KB
constexpr long long WS_WHH8   = WS_F8 + 98304;              // 192KB
constexpr long long WS_WHIST8 = WS_F8 + 294912;             // 28KB
constexpr long long WS_WR8    = WS_F8 + 323584;             // 14KB
constexpr long long WS_WIHM8  = WS_F8 + 337920;             // 96KB (m-part of W_ih, fp8)
constexpr long long WS_LOSSP  = WS_F8 + 436224;             // 128 f32

DEV u16 cvt_bf16(float f) {
  union { float f; u32 u; } v; v.f = f;
  u32 u = v.u;
  return (u16)((u + 0x7fffu + ((u >> 16) & 1u)) >> 16);
}
DEV float cvt_f32(u16 h) {
  union { u32 u; float f; } v; v.u = ((u32)h) << 16;
  return v.f;
}
DEV u32 enc_e4m3(float f) {
  union { float f; u32 u; } v; v.f = f;
  u32 sign = (v.u >> 24) & 0x80u;
  v.u &= 0x7fffffffu;
  float a = fminf(v.f, 448.f);
  if (a < 0.015625f) {
    int mq = (int)rintf(a * 512.f);
    return sign | (u32)mq;
  }
  union { float f; u32 u; } w; w.f = a;
  u32 lsb = (w.u >> 20) & 1u;
  u32 r = w.u + 0x7FFFFu + lsb;
  u32 E = ((r >> 23) & 0xffu) - 120u;
  u32 M = (r >> 20) & 7u;
  if (E >= 16u) { E = 15u; M = 6u; }
  return sign | (E << 3) | M;
}
DEV u32 cvtfp8(float a) {
  u32 r;
  asm("v_cvt_pk_fp8_f32 %0, %1, %2" : "=v"(r) : "v"(a), "v"(a));
  return r;
}
DEV u32 cvtfp8x2(float a, float b) {
  u32 r;
  asm("v_cvt_pk_fp8_f32 %0, %1, %2" : "=v"(r) : "v"(a), "v"(b));
  return r & 0xffffu;
}
DEV u32 pkbf(float a, float b) {
  u32 r;
  asm("v_cvt_pk_bf16_f32 %0, %1, %2" : "=v"(r) : "v"(a), "v"(b));
  return r;
}
#if __has_builtin(__builtin_amdgcn_cvt_pk_f32_fp8)
DEV f32x4 dec8x4(u32 w) {
  f32x2 lo = __builtin_amdgcn_cvt_pk_f32_fp8((int)w, false);
  f32x2 hi = __builtin_amdgcn_cvt_pk_f32_fp8((int)w, true);
  return (f32x4){lo[0], lo[1], hi[0], hi[1]};
}
#else
DEV float dec8(u32 b) {
  u32 e = (b >> 3) & 0xfu, mm = b & 7u, s = b >> 7;
  union { u32 u; float f; } v;
  v.u = (s << 31) | ((e + 120u) << 23) | (mm << 20);
  return e ? v.f : 0.f;
}
DEV f32x4 dec8x4(u32 w) {
  return (f32x4){dec8(w & 0xff), dec8((w >> 8) & 0xff), dec8((w >> 16) & 0xff), dec8(w >> 24)};
}
#endif
DEV s16x8 mk8(f32x4 lo, f32x4 hi) {
  union { u32 q[4]; s16x8 v; } u;
  u.q[0] = pkbf(lo[0], lo[1]); u.q[1] = pkbf(lo[2], lo[3]);
  u.q[2] = pkbf(hi[0], hi[1]); u.q[3] = pkbf(hi[2], hi[3]);
  return u.v;
}
DEV f32x4 l4(const float* p) { return (f32x4)(*(const f32x4u*)p); }
DEV f32x4 mfma16(s16x8 a, s16x8 b, f32x4 c) {
  return __builtin_amdgcn_mfma_f32_16x16x32_bf16(a, b, c, 0, 0, 0);
}
DEV f32x4 mfma8(i64 a, i64 b, f32x4 c) {
  return __builtin_amdgcn_mfma_f32_16x16x32_fp8_fp8(a, b, c, 0, 0, 0);
}
DEV s16x8 ldB(const u16* w, int frag, int lane) {
  return *reinterpret_cast<const s16x8*>(w + ((long long)frag * 64 + lane) * 8);
}
DEV float sigm(float v) { return 1.f / (1.f + __expf(-v)); }
DEV float tanhx(float v) {
  float e = __expf(-2.f * fabsf(v));
  float t = (1.f - e) / (1.f + e);
  return v < 0.f ? -t : t;
}
// lgkm-only barrier: orders LDS producer->consumer without draining vmem queues.
// Global loads issued before it stay in flight; compiler inserts vmcnt waits at first use.
DEV void barL() {
  asm volatile("s_waitcnt lgkmcnt(0)\n\ts_barrier" ::: "memory");
}

// ---------------- K0: pack bf16 MFMA-B fragments (k2's weights); zero msum ----------------
__global__ __launch_bounds__(256) void k0_pack(
    const float* __restrict__ W_td, const float* __restrict__ W_u, const float* __restrict__ W_v,
    const float* __restrict__ W_r,
    float* __restrict__ msum, u16* __restrict__ wsu) {
  if (blockIdx.x == 37) {
    if (threadIdx.x < T_) msum[threadIdx.x] = 0.f;
    return;
  }
  int frag = blockIdx.x * 4 + (threadIdx.x >> 6);
  int lane = threadIdx.x & 63;
  const float* src; long long off; int kmax, nmax, stride, diag = 0, f;
  if (frag < 64)       { f = frag;       src = W_td; off = WS_WTD; stride = 99; kmax = 99; nmax = 256; }
  else if (frag < 92)  { f = frag - 64;  src = W_u;  off = WS_WU;  stride = 99; kmax = 99; nmax = 99;  }
  else if (frag < 120) { f = frag - 92;  src = W_v;  off = WS_WV;  stride = 99; kmax = 99; nmax = 99;  diag = 1; }
  else if (frag < 148) { f = frag - 120; src = W_r;  off = WS_WRB; stride = 99; kmax = 99; nmax = 99;  diag = 1; }
  else return;
  int nt = f / 4, kc = f % 4;
  int n = nt * 16 + (lane & 15);
  u16* dst = wsu + off / 2 + ((long long)f * 64 + lane) * 8;
#pragma unroll
  for (int j = 0; j < 8; j++) {
    int k = kc * 32 + ((lane >> 4) << 3) + j;
    float v = 0.f;
    if (k < kmax && n < nmax && !(diag && k == n)) v = src[(long long)n * stride + k];
    dst[j] = cvt_bf16(v);
  }
}

// ---------------- K0b: pack fp8 e4m3 B-fragments (x16) ----------------
__global__ __launch_bounds__(256) void k0b_pack8(
    const float* __restrict__ W_ih, const float* __restrict__ W_hh,
    const float* __restrict__ W_hist, const float* __restrict__ W_r, u8* __restrict__ ws8) {
  int frag = blockIdx.x * 4 + (threadIdx.x >> 6);
  int lane = threadIdx.x & 63;
  const float* src; long long off; int KC, koff, kmax, nmax, stride, diag = 0, f;
  if (frag < 192)      { f = frag;       src = W_ih;   off = WS_WIHX8;  KC = 4; stride = 198; koff = 0; kmax = 99;  nmax = 768; }
  else if (frag < 576) { f = frag - 192; src = W_hh;   off = WS_WHH8;   KC = 8; stride = 256; koff = 0; kmax = 256; nmax = 768; }
  else if (frag < 632) { f = frag - 576; src = W_hist; off = WS_WHIST8; KC = 8; stride = 256; koff = 0; kmax = 256; nmax = 99;  }
  else if (frag < 660) { f = frag - 632; src = W_r;    off = WS_WR8;    KC = 4; stride = 99;  koff = 0; kmax = 99;  nmax = 99;  diag = 1; }
  else if (frag < 852) { f = frag - 660; src = W_ih;   off = WS_WIHM8;  KC = 4; stride = 198; koff = 99; kmax = 99; nmax = 768; }
  else return;
  int nt = f / KC, kc = f % KC;
  int n = nt * 16 + (lane & 15);
  u64 r = 0;
#pragma unroll
  for (int j = 0; j < 8; j++) {
    int k = kc * 32 + ((lane >> 4) << 3) + j;
    float v = 0.f;
    if (k < kmax && n < nmax && !(diag && k == n)) v = src[(long long)n * stride + koff + k] * 16.f;
    r |= (u64)enc_e4m3(v) << (8 * j);
  }
  *reinterpret_cast<u64*>(ws8 + off + ((long long)f * 64 + lane) * 8) = r;
}

// ---------------- K2: parallel precompute ----------------
// grid 1600: one wave per (batch-chunk bc in [0,32), t). gim via fp8 MFMA (m is 0x50-coded fp8).
__global__ __launch_bounds__(256) void k2_pre(
    const float* __restrict__ x, const float* __restrict__ xh, const float* __restrict__ uu,
    const float* __restrict__ m, const float* __restrict__ dd,
    const float* __restrict__ b_td, const float* __restrict__ b_u, const float* __restrict__ b_v,
    const float* __restrict__ b_r, const float* __restrict__ b_ih,
    float* __restrict__ msum, float* __restrict__ out, u16* __restrict__ wsu) {
  const int tid = threadIdx.x, w = tid >> 6, lane = tid & 63;
  const int bc = blockIdx.x & 31, tg = blockIdx.x >> 5;
  const int t = tg * 4 + w;
  const int b0 = bc * 16;
  const int cl = lane & 15, rq = (lane >> 4) << 2, kr8 = (lane >> 4) << 3;
  const long long gb = (long long)(b0 + cl) * TV_ + (long long)t * V_;
  u8* ws8 = reinterpret_cast<u8*>(wsu);
  const u16* wtd = wsu + WS_WTD / 2;
  const u16* wu  = wsu + WS_WU / 2;
  const u16* wv  = wsu + WS_WV / 2;
  const u16* wrb = wsu + WS_WRB / 2;
  const u64* wm8 = reinterpret_cast<const u64*>(ws8 + WS_WIHM8);
  u16* gam = wsu + WS_GAMMA / 2;
  u16* xrp = wsu + WS_XRPRE / 2;
  u16* x16p = wsu + WS_X16 / 2;
  u16* xu16p = wsu + WS_XUS16 / 2;
  u8* m8p = ws8 + WS_M8;
  u8* gim8p = ws8 + WS_GIM8;
  const f32x4 z4 = {0.f, 0.f, 0.f, 0.f};
  constexpr float inv128 = 1.f / 128.f;

  // ---- gamma ----
  {
    s16x8 fd[4];
#pragma unroll
    for (int kc = 0; kc < 3; kc++) {
      int k0 = kc * 32 + kr8;
      fd[kc] = mk8(l4(dd + gb + k0), l4(dd + gb + k0 + 4));
    }
    {
      f32x4 a = z4;
      if (kr8 == 0) { a[0] = dd[gb + 96]; a[1] = dd[gb + 97]; a[2] = dd[gb + 98]; }
      fd[3] = mk8(a, z4);
    }
    for (int nt = 0; nt < 16; nt++) {
      int col = nt * 16 + cl;
      float bt = b_td[col];
      f32x4 a = {bt, bt, bt, bt};
#pragma unroll
      for (int kc = 0; kc < 4; kc++) a = mfma16(fd[kc], ldB(wtd, nt * 4 + kc, lane), a);
#pragma unroll
      for (int j = 0; j < 4; j++) {
        int b = b0 + rq + j;
        gam[((long long)t * B_ + b) * H_ + col] = cvt_bf16(__expf(-fmaxf(a[j], 0.f)));
      }
    }
  }

  // ---- gather pass: frags + x16 / m8 + fp8 m-frags ----
  s16x8 fu[4], fxb[4], fmx[4];
  u64 fm8[4];
  float mpart = 0.f;
  const long long rowoff = (long long)t * B_ + (b0 + cl);
  u16* x16row = x16p + rowoff * 100;
  u8* m8row = m8p + rowoff * 104;
#pragma unroll
  for (int kc = 0; kc < 3; kc++) {
    int k0 = kc * 32 + kr8;
    f32x4 u0 = l4(uu + gb + k0), u1 = l4(uu + gb + k0 + 4);
    f32x4 m0 = l4(m + gb + k0),  m1 = l4(m + gb + k0 + 4);
    f32x4 x0 = l4(x + gb + k0),  x1 = l4(x + gb + k0 + 4);
    f32x4 h0 = l4(xh + gb + k0), h1 = l4(xh + gb + k0 + 4);
    fu[kc]  = mk8(u0, u1);
    fmx[kc] = mk8(m0 * x0, m1 * x1);
    fxb[kc] = mk8(h0 + m0 * (x0 - h0), h1 + m1 * (x1 - h1));
    mpart += m0[0] + m0[1] + m0[2] + m0[3] + m1[0] + m1[1] + m1[2] + m1[3];
    u64 xw0 = (u64)pkbf(x0[0], x0[1]) | ((u64)pkbf(x0[2], x0[3]) << 32);
    u64 xw1 = (u64)pkbf(x1[0], x1[1]) | ((u64)pkbf(x1[2], x1[3]) << 32);
    *reinterpret_cast<u64*>(x16row + k0) = xw0;
    *reinterpret_cast<u64*>(x16row + k0 + 4) = xw1;
    u64 mb = 0;
#pragma unroll
    for (int e = 0; e < 4; e++) {
      mb |= (m0[e] > 0.5f ? 0x50ull : 0ull) << (8 * e);
      mb |= (m1[e] > 0.5f ? 0x50ull : 0ull) << (32 + 8 * e);
    }
    *reinterpret_cast<u64*>(m8row + k0) = mb;
    fm8[kc] = mb;
  }
  {
    f32x4 u0 = z4, m0 = z4, x0 = z4, h0 = z4;
    u64 mb = 0;
    if (kr8 == 0) {
#pragma unroll
      for (int e = 0; e < 3; e++) {
        u0[e] = uu[gb + 96 + e]; m0[e] = m[gb + 96 + e];
        x0[e] = x[gb + 96 + e];  h0[e] = xh[gb + 96 + e];
      }
#pragma unroll
      for (int e = 0; e < 3; e++) {
        x16row[96 + e] = cvt_bf16(x0[e]);
        m8row[96 + e] = (m0[e] > 0.5f) ? 0x50 : 0;
        mb |= (m0[e] > 0.5f ? 0x50ull : 0ull) << (8 * e);
      }
    }
    fu[3]  = mk8(u0, z4);
    fmx[3] = mk8(m0 * x0, z4);
    fxb[3] = mk8(h0 + m0 * (x0 - h0), z4);
    fm8[3] = mb;
    mpart += m0[0] + m0[1] + m0[2];
  }
  {
    float mp = mpart;
#pragma unroll
    for (int s = 32; s; s >>= 1) mp += __shfl_xor(mp, s);
    if (lane == 0) atomicAdd(&msum[t], mp);
  }

  // ---- V-wide GEMMs: unc / xu / xr_pre ----
  for (int nt = 0; nt < 7; nt++) {
    int col = nt * 16 + cl;
    float bu_ = 0.f, bv_ = 0.f, br_ = 0.f;
    if (col < V_) { bu_ = b_u[col]; bv_ = b_v[col]; br_ = b_r[col]; }
    f32x4 au = {bu_, bu_, bu_, bu_}, av = {bv_, bv_, bv_, bv_}, ar = {br_, br_, br_, br_};
#pragma unroll
    for (int kc = 0; kc < 4; kc++) {
      au = mfma16(fu[kc],  ldB(wu, nt * 4 + kc, lane), au);
      av = mfma16(fxb[kc], ldB(wv, nt * 4 + kc, lane), av);
      ar = mfma16(fmx[kc], ldB(wrb, nt * 4 + kc, lane), ar);
    }
    if (col < V_) {
#pragma unroll
      for (int j = 0; j < 4; j++) {
        int b = b0 + rq + j;
        float unc = __expf(-fmaxf(au[j], 0.f));
        float xuv = av[j] * unc;
        out[XUS_O + (long long)b * TV_ + (long long)t * V_ + col] = xuv;
        xu16p[((long long)t * B_ + b) * V_ + col] = cvt_bf16(xuv);
        xrp[((long long)t * B_ + b) * V_ + col] = cvt_bf16(ar[j]);
      }
    }
  }
  // ---- gim8 = fp8( (b_ih + m @ W_ihm) * 64 ), via fp8 MFMA (m x8, W x16 -> acc/128) ----
  for (int nt = 0; nt < 48; nt++) {
    int col = nt * 16 + cl;
    float bi = b_ih[col];
    f32x4 a = z4;
#pragma unroll
    for (int kc = 0; kc < 4; kc++)
      a = mfma8((i64)fm8[kc], (i64)wm8[(long long)(nt * 4 + kc) * 64 + lane], a);
    float g0 = (a[0] * inv128 + bi) * 64.f, g1 = (a[1] * inv128 + bi) * 64.f;
    float g2 = (a[2] * inv128 + bi) * 64.f, g3 = (a[3] * inv128 + bi) * 64.f;
    u32 p = cvtfp8x2(g0, g1) | (cvtfp8x2(g2, g3) << 16);
    *reinterpret_cast<u32*>(gim8p + (((long long)t * 32 + bc) * 48 + nt) * 256 + (long long)lane * 4) = p;
  }
}

// ---------------- K_SEQ: persistent scan; 128 WGs x 4 rows x 1024 threads ----------------
// R9 structure + lgkm-only in-loop barriers + one-step-ahead m8 prefetch.
__global__ void __attribute__((amdgpu_flat_work_group_size(1024, 1024), amdgpu_waves_per_eu(4, 4)))
k_seq(
    const float* __restrict__ b_hist, const float* __restrict__ b_hh,
    const float* __restrict__ conv_w, const float* __restrict__ conv_b,
    const float* __restrict__ W_fc, const float* __restrict__ b_fc,
    const float* __restrict__ msum, float* out, u16* wsu) {
  __shared__ __align__(16) u8 hp8_s[16 * 272];
  __shared__ __align__(16) u8 e8_s[16 * 144];
  __shared__ __align__(16) u8 xi8_s[16 * 144];
  __shared__ __align__(16) u8 whhR_l[65536];
  __shared__ __align__(16) u8 whist8_l[28672];
  __shared__ __align__(16) u8 wr8_l[14336];
  __shared__ __align__(16) float hf_s[4][260];
  __shared__ float red_s[1024];

  const int tid = threadIdx.x, wv = tid >> 6, lane = tid & 63;
  const int cl = lane & 15, rq = (lane >> 4) << 2, kr8 = (lane >> 4) << 3;
  const int b0 = blockIdx.x * 4;
  const int cc = blockIdx.x >> 2, quarter = blockIdx.x & 3;
  const u8* ws8 = reinterpret_cast<const u8*>(wsu);

  for (int i = tid; i < 1088; i += 1024) reinterpret_cast<u32*>(hp8_s)[i] = 0;
  for (int i = tid; i < 576; i += 1024) { reinterpret_cast<u32*>(e8_s)[i] = 0; reinterpret_cast<u32*>(xi8_s)[i] = 0; }
  {
    const u32* s0 = reinterpret_cast<const u32*>(ws8 + WS_WHH8);
    u32* d0 = reinterpret_cast<u32*>(whhR_l);
    for (int i = tid; i < 16384; i += 1024) d0[i] = s0[i];
    const u32* s1 = reinterpret_cast<const u32*>(ws8 + WS_WHIST8);
    u32* d1 = reinterpret_cast<u32*>(whist8_l);
    for (int i = tid; i < 7168; i += 1024) d1[i] = s1[i];
    const u32* s2 = reinterpret_cast<const u32*>(ws8 + WS_WR8);
    u32* d2 = reinterpret_cast<u32*>(wr8_l);
    for (int i = tid; i < 3584; i += 1024) d2[i] = s2[i];
  }

  // resident fp8 weights: wihx (3 gates) + whh z,n
  const u64* wx8 = reinterpret_cast<const u64*>(ws8 + WS_WIHX8);
  const u64* wh8 = reinterpret_cast<const u64*>(ws8 + WS_WHH8);
  i64 wihx_r[3][4];
  i64 whhZ[8], whhN[8];
#pragma unroll
  for (int gg = 0; gg < 3; gg++)
#pragma unroll
    for (int kc = 0; kc < 4; kc++)
      wihx_r[gg][kc] = (i64)wx8[(long long)((gg * 16 + wv) * 4 + kc) * 64 + lane];
#pragma unroll
  for (int kc = 0; kc < 8; kc++) {
    whhZ[kc] = (i64)wh8[(long long)((16 + wv) * 8 + kc) * 64 + lane];
    whhN[kc] = (i64)wh8[(long long)((32 + wv) * 8 + kc) * 64 + lane];
  }

  const int col = wv * 16 + cl;
  const float bhh0 = b_hh[col], bhh1 = b_hh[256 + col], bhh2 = b_hh[512 + col];
  const bool rowok = (rq < 4);
  const bool vwave = (wv < 7);
  const int vcol = col;
  const bool vact = vwave && (vcol < V_);
  const bool vld = vact && rowok;
  const float bh = vact ? b_hist[vcol] : 0.f;
  const float cw0 = conv_w[0], cw1 = conv_w[1], cb = conv_b[0];

  const u16* gamp = wsu + WS_GAMMA / 2;
  const u16* x16p = wsu + WS_X16 / 2;
  const u16* xu16p = wsu + WS_XUS16 / 2;
  const u16* xrpp = wsu + WS_XRPRE / 2;
  const u8* m8p = ws8 + WS_M8;
  int lane_p = ((quarter + (rq >> 2)) * 16 + cl) & 63;
  const u8* gimp = ws8 + WS_GIM8 + (((long long)cc * 48 + wv) * 64 + lane_p) * 4;

  u32 gaidx = BH_ + (u32)(b0 + rq) * H_ + col;
  u32 xidx = (u32)(b0 + rq) * 100 + vcol;
  u32 xuidx = (u32)(b0 + rq) * 99 + vcol;
  u32 midx = (u32)(b0 + rq) * 104 + vcol;
  u32 gidx = (u32)(b0 + rq) * TV_ + vcol;

  float hpr[4] = {0.f, 0.f, 0.f, 0.f};
  float loss_acc = 0.f;
  constexpr float inv128 = 1.f / 128.f;
  constexpr float inv64 = 1.f / 64.f;
  const f32x4 z4 = {0.f, 0.f, 0.f, 0.f};

  // prefetch m8 for t=0 (consumed in P1, which no barrier can cover in-step)
  u8 cmC[4] = {0, 0, 0, 0};
  if (vld) {
#pragma unroll
    for (int j = 0; j < 4; j++) cmC[j] = m8p[midx + (u32)j * 104];
  }
  __syncthreads();

  for (int t = 0; t < T_; t++) {
    // ---- step-top: issue all global loads (m8 for t+1; rest for t) ----
    u32 gimw0, gimw1, gimw2;
    {
      const u32* gp = reinterpret_cast<const u32*>(gimp + (long long)t * 393216);
      gimw0 = gp[0]; gimw1 = gp[1024]; gimw2 = gp[2048];
    }
    u16 ga[4] = {0, 0, 0, 0};
    if (rowok && t + 1 < T_) {
#pragma unroll
      for (int j = 0; j < 4; j++) ga[j] = gamp[gaidx + (u32)j * H_];
    }
    gaidx += BH_;
    u16 cx16[4] = {0, 0, 0, 0}, cxu[4] = {0, 0, 0, 0}, cxr[4] = {0, 0, 0, 0};
    u8 cmN[4] = {0, 0, 0, 0};
    if (vld) {
#pragma unroll
      for (int j = 0; j < 4; j++) {
        cx16[j] = x16p[xidx + (u32)j * 100];
        cxu[j]  = xu16p[xuidx + (u32)j * 99];
        cxr[j]  = xrpp[xuidx + (u32)j * 99];
      }
      if (t + 1 < T_) {
        const u32 mi2 = midx + B_ * 104;
#pragma unroll
        for (int j = 0; j < 4; j++) cmN[j] = m8p[mi2 + (u32)j * 104];
      }
    }
    xidx += B_ * 100; xuidx += B_ * 99; midx += B_ * 104;
    const float msv = msum[t];

    // ---- P1: gh chains + x_h ----
    f32x4 accR = z4, accZ = z4, accNh = z4, accXh = z4;
#pragma unroll
    for (int kc = 0; kc < 8; kc++) {
      const i64 a = *reinterpret_cast<const i64*>(&hp8_s[cl * 272 + kc * 32 + kr8]);
      const i64 br = *reinterpret_cast<const i64*>(&whhR_l[(wv * 8 + kc) * 512 + lane * 8]);
      accR  = mfma8(a, br, accR);
      accZ  = mfma8(a, whhZ[kc], accZ);
      accNh = mfma8(a, whhN[kc], accNh);
      if (vwave) {
        const i64 bw = *reinterpret_cast<const i64*>(&whist8_l[(wv * 8 + kc) * 512 + lane * 8]);
        accXh = mfma8(a, bw, accXh);
      }
    }
    if (vld) {
#pragma unroll
      for (int j = 0; j < 4; j++) {
        const float xhv = accXh[j] * inv128 + bh;
        const float ev = cmC[j] ? 0.f : xhv;
        e8_s[(rq + j) * 144 + vcol] = (u8)cvtfp8(ev * 8.f);
      }
    }
    barL();

    // ---- P2: xr, x_comb, loss, x_imp, xrs ----
    if (vwave) {
      f32x4 acc = z4;
#pragma unroll
      for (int kc = 0; kc < 4; kc++) {
        const i64 a = *reinterpret_cast<const i64*>(&e8_s[cl * 144 + kc * 32 + kr8]);
        const i64 b = *reinterpret_cast<const i64*>(&wr8_l[(wv * 4 + kc) * 512 + lane * 8]);
        acc = mfma8(a, b, acc);
      }
      if (vld) {
        const float inv_ms = 1.f / (msv + 1e-5f);
        float ls = 0.f;
#pragma unroll
        for (int j = 0; j < 4; j++) {
          const float xrv = acc[j] * inv128 + cvt_f32(cxr[j]);
          const float xc = cw0 * cvt_f32(cxu[j]) + cw1 * xrv + cb;
          const float xj = cvt_f32(cx16[j]);
          const bool mj = cmC[j] != 0;
          const float ximp = mj ? xj : xc;
          ls += mj ? fabsf(xj - xc) : 0.f;
          const u32 gj = gidx + (u32)j * TV_;
          out[XIMP_O + gj] = ximp;
          out[XRS_O + gj] = xrv;
          xi8_s[(rq + j) * 144 + vcol] = (u8)cvtfp8(ximp * 8.f);
        }
        loss_acc += ls * inv_ms;
      }
    }
    gidx += V_;
    barL();

    // ---- P3: gi x-part + GRU update (+ fused gamma[t+1]) ----
    f32x4 accNx = z4;
#pragma unroll
    for (int kc = 0; kc < 4; kc++) {
      const i64 a = *reinterpret_cast<const i64*>(&xi8_s[cl * 144 + kc * 32 + kr8]);
      accR  = mfma8(a, wihx_r[0][kc], accR);
      accZ  = mfma8(a, wihx_r[1][kc], accZ);
      accNx = mfma8(a, wihx_r[2][kc], accNx);
    }
    const f32x4 gimR = dec8x4(gimw0);
    const f32x4 gimZ = dec8x4(gimw1);
    const f32x4 gimN = dec8x4(gimw2);
#pragma unroll
    for (int j = 0; j < 4; j++) {
      const float rr = sigm(accR[j] * inv128 + gimR[j] * inv64 + bhh0);
      const float zz = sigm(accZ[j] * inv128 + gimZ[j] * inv64 + bhh1);
      const float gin = accNx[j] * inv128 + gimN[j] * inv64;
      const float ghn = accNh[j] * inv128 + bhh2;
      const float nn = tanhx(gin + rr * ghn);
      const float hn = (1.f - zz) * nn + zz * hpr[j];
      if (t + 1 < T_) {
        const float hpnew = hn * cvt_f32(ga[j]);
        hpr[j] = hpnew;
        if (rowok) hp8_s[(rq + j) * 272 + col] = (u8)cvtfp8(hpnew * 8.f);
      } else {
        if (rowok) hf_s[rq + j][col] = hn;
      }
    }
    // rotate m8 prefetch
    cmC[0] = cmN[0]; cmC[1] = cmN[1]; cmC[2] = cmN[2]; cmC[3] = cmN[3];
    barL();
  }

  // ---- epilogue ----
  if (tid < 4) {
    float acc = 0.f;
    for (int k = 0; k < H_; k++) acc += hf_s[tid][k] * W_fc[k];
    const float yv = acc + b_fc[0];
    out[YOUT_O + b0 + tid] = yv;
    out[YSC_O + b0 + tid] = 1.f / (1.f + __expf(-yv));
  }
  red_s[tid] = loss_acc;
  __syncthreads();
  for (int s = 512; s; s >>= 1) {
    if (tid < s) red_s[tid] += red_s[tid + s];
    __syncthreads();
  }
  if (tid == 0) {
    float* lp = reinterpret_cast<float*>(reinterpret_cast<char*>(wsu) + WS_LOSSP);
    lp[blockIdx.x] = red_s[0];
  }
}

// ---------------- K3: deterministic loss reduction ----------------
__global__ void k3_loss(const float* __restrict__ lossp, float* __restrict__ out) {
  if (threadIdx.x == 0) {
    float s = 0.f;
    for (int i = 0; i < 128; i++) s += lossp[i];
    out[LOSS_O] = s;
  }
}

extern "C" void kernel_launch(void* const* d_in, const int* in_sizes, int n_in,
                              void* d_out, int out_size, void* d_ws, size_t ws_size,
                              hipStream_t stream) {
  (void)in_sizes; (void)n_in; (void)out_size; (void)ws_size;
  const float* x      = (const float*)d_in[0];
  const float* xhat   = (const float*)d_in[1];
  const float* u      = (const float*)d_in[2];
  const float* m      = (const float*)d_in[3];
  const float* d      = (const float*)d_in[4];
  const float* W_td   = (const float*)d_in[6];
  const float* b_td   = (const float*)d_in[7];
  const float* W_hist = (const float*)d_in[8];
  const float* b_hist = (const float*)d_in[9];
  const float* W_v    = (const float*)d_in[10];
  const float* b_v    = (const float*)d_in[11];
  const float* W_r    = (const float*)d_in[12];
  const float* b_r    = (const float*)d_in[13];
  const float* W_u    = (const float*)d_in[14];
  const float* b_u    = (const float*)d_in[15];
  const float* conv_w = (const float*)d_in[16];
  const float* conv_b = (const float*)d_in[17];
  const float* W_ih   = (const float*)d_in[18];
  const float* b_ih   = (const float*)d_in[19];
  const float* W_hh   = (const float*)d_in[20];
  const float* b_hh   = (const float*)d_in[21];
  const float* W_fc   = (const float*)d_in[22];
  const float* b_fc   = (const float*)d_in[23];
  float* out = (float*)d_out;
  u16* wsu = (u16*)d_ws;
  float* msum = (float*)d_ws;
  const float* lossp = (const float*)((char*)d_ws + WS_LOSSP);

  hipLaunchKernelGGL(k0_pack, dim3(38), dim3(256), 0, stream,
                     W_td, W_u, W_v, W_r, msum, wsu);
  hipLaunchKernelGGL(k0b_pack8, dim3(213), dim3(256), 0, stream,
                     W_ih, W_hh, W_hist, W_r, (u8*)d_ws);
  hipLaunchKernelGGL(k2_pre, dim3(1600), dim3(256), 0, stream,
                     x, xhat, u, m, d, b_td, b_u, b_v, b_r, b_ih, msum, out, wsu);
  hipLaunchKernelGGL(k_seq, dim3(128), dim3(1024), 0, stream,
                     b_hist, b_hh, conv_w, conv_b, W_fc, b_fc, msum, out, wsu);
  hipLaunchKernelGGL(k3_loss, dim3(1), dim3(64), 0, stream, lossp, out);
}

// Round 11
// 1291.851 us; speedup vs baseline: 1.0789x; 1.0789x over previous
//
#include <hip/hip_runtime.h>

typedef unsigned short u16;
typedef unsigned int   u32;
typedef unsigned char  u8;
typedef unsigned long long u64;
typedef long i64;
typedef __attribute__((ext_vector_type(8))) short s16x8;
typedef __attribute__((ext_vector_type(4))) float f32x4;
typedef __attribute__((ext_vector_type(2))) float f32x2;
typedef __attribute__((ext_vector_type(4), aligned(4))) float f32x4u;

#define DEV static __device__ __forceinline__

constexpr int B_ = 512, T_ = 200, V_ = 99, H_ = 256;
constexpr int TV_ = T_ * V_;
constexpr u32 BH_ = B_ * H_;

// d_out f32 element offsets: (x_imp, y_out, y_score, x_loss, xus, xrs)
constexpr long long XIMP_O = 0;
constexpr long long YOUT_O = 10137600;
constexpr long long YSC_O  = 10138112;
constexpr long long LOSS_O = 10138624;
constexpr long long XUS_O  = 10138625;
constexpr long long XRS_O  = 20276225;

// ---- workspace byte offsets ----
constexpr long long WS_MSUM   = 0;                          // 200 f32
constexpr long long WS_GAMMA  = 1024;                       // [T][B][H] bf16
constexpr long long WS_XRPRE  = 52429824;                   // [T][B][99] bf16
constexpr long long WS_X16    = 72705024;                   // [T][B][100] bf16
constexpr long long WS_XUS16  = 93185024;                   // [T][B][99] bf16
constexpr long long WS_M8     = 113460224;                  // [T][B][104] u8
constexpr long long WS_GIM8   = 124109824;                  // [T][32][48][64][4] u8 (78,643,200)
constexpr long long WS_WTD    = 202753024;                  // bf16 packs (k2)
constexpr long long WS_WU     = WS_WTD + 65536;
constexpr long long WS_WV     = WS_WU + 28672;
constexpr long long WS_WRB    = WS_WV + 28672;
constexpr long long WS_F8     = WS_WRB + 28672;             // fp8 packs
constexpr long long WS_WIHX8  = WS_F8;                      // 96KB
constexpr long long WS_WHH8   = WS_F8 + 98304;              // 192KB
constexpr long long WS_WHIST8 = WS_F8 + 294912;             // 28KB
constexpr long long WS_WR8    = WS_F8 + 323584;             // 14KB
constexpr long long WS_WIHM8  = WS_F8 + 337920;             // 96KB (m-part of W_ih, fp8)
constexpr long long WS_LOSSP  = WS_F8 + 436224;             // 128 f32

DEV u16 cvt_bf16(float f) {
  union { float f; u32 u; } v; v.f = f;
  u32 u = v.u;
  return (u16)((u + 0x7fffu + ((u >> 16) & 1u)) >> 16);
}
DEV float cvt_f32(u16 h) {
  union { u32 u; float f; } v; v.u = ((u32)h) << 16;
  return v.f;
}
DEV u32 enc_e4m3(float f) {
  union { float f; u32 u; } v; v.f = f;
  u32 sign = (v.u >> 24) & 0x80u;
  v.u &= 0x7fffffffu;
  float a = fminf(v.f, 448.f);
  if (a < 0.015625f) {
    int mq = (int)rintf(a * 512.f);
    return sign | (u32)mq;
  }
  union { float f; u32 u; } w; w.f = a;
  u32 lsb = (w.u >> 20) & 1u;
  u32 r = w.u + 0x7FFFFu + lsb;
  u32 E = ((r >> 23) & 0xffu) - 120u;
  u32 M = (r >> 20) & 7u;
  if (E >= 16u) { E = 15u; M = 6u; }
  return sign | (E << 3) | M;
}
DEV u32 cvtfp8(float a) {
  u32 r;
  asm("v_cvt_pk_fp8_f32 %0, %1, %2" : "=v"(r) : "v"(a), "v"(a));
  return r;
}
DEV u32 cvtfp8x2(float a, float b) {
  u32 r;
  asm("v_cvt_pk_fp8_f32 %0, %1, %2" : "=v"(r) : "v"(a), "v"(b));
  return r & 0xffffu;
}
DEV u32 pkbf(float a, float b) {
  u32 r;
  asm("v_cvt_pk_bf16_f32 %0, %1, %2" : "=v"(r) : "v"(a), "v"(b));
  return r;
}
#if __has_builtin(__builtin_amdgcn_cvt_pk_f32_fp8)
DEV f32x4 dec8x4(u32 w) {
  f32x2 lo = __builtin_amdgcn_cvt_pk_f32_fp8((int)w, false);
  f32x2 hi = __builtin_amdgcn_cvt_pk_f32_fp8((int)w, true);
  return (f32x4){lo[0], lo[1], hi[0], hi[1]};
}
#else
DEV float dec8(u32 b) {
  u32 e = (b >> 3) & 0xfu, mm = b & 7u, s = b >> 7;
  union { u32 u; float f; } v;
  v.u = (s << 31) | ((e + 120u) << 23) | (mm << 20);
  return e ? v.f : 0.f;
}
DEV f32x4 dec8x4(u32 w) {
  return (f32x4){dec8(w & 0xff), dec8((w >> 8) & 0xff), dec8((w >> 16) & 0xff), dec8(w >> 24)};
}
#endif
DEV s16x8 mk8(f32x4 lo, f32x4 hi) {
  union { u32 q[4]; s16x8 v; } u;
  u.q[0] = pkbf(lo[0], lo[1]); u.q[1] = pkbf(lo[2], lo[3]);
  u.q[2] = pkbf(hi[0], hi[1]); u.q[3] = pkbf(hi[2], hi[3]);
  return u.v;
}
DEV f32x4 l4(const float* p) { return (f32x4)(*(const f32x4u*)p); }
DEV f32x4 mfma16(s16x8 a, s16x8 b, f32x4 c) {
  return __builtin_amdgcn_mfma_f32_16x16x32_bf16(a, b, c, 0, 0, 0);
}
DEV f32x4 mfma8(i64 a, i64 b, f32x4 c) {
  return __builtin_amdgcn_mfma_f32_16x16x32_fp8_fp8(a, b, c, 0, 0, 0);
}
DEV s16x8 ldB(const u16* w, int frag, int lane) {
  return *reinterpret_cast<const s16x8*>(w + ((long long)frag * 64 + lane) * 8);
}
DEV float sigm(float v) { return 1.f / (1.f + __expf(-v)); }
DEV float tanhx(float v) {
  float e = __expf(-2.f * fabsf(v));
  float t = (1.f - e) / (1.f + e);
  return v < 0.f ? -t : t;
}

// ---------------- K0: merged pack (bf16 + fp8 fragments); zero msum ----------------
// blocks 0-36: bf16 frags 0-147 | block 37: msum zero | blocks 38-250: fp8 frags 0-851
__global__ __launch_bounds__(256) void k0_all(
    const float* __restrict__ W_td, const float* __restrict__ W_u, const float* __restrict__ W_v,
    const float* __restrict__ W_r, const float* __restrict__ W_ih, const float* __restrict__ W_hh,
    const float* __restrict__ W_hist,
    float* __restrict__ msum, u16* __restrict__ wsu) {
  const int blk = blockIdx.x;
  if (blk == 37) {
    if (threadIdx.x < T_) msum[threadIdx.x] = 0.f;
    return;
  }
  const int lane = threadIdx.x & 63;
  if (blk < 37) {
    // bf16 packs for k2
    int frag = blk * 4 + (threadIdx.x >> 6);
    const float* src; long long off; int kmax, nmax, stride, diag = 0, f;
    if (frag < 64)       { f = frag;       src = W_td; off = WS_WTD; stride = 99; kmax = 99; nmax = 256; }
    else if (frag < 92)  { f = frag - 64;  src = W_u;  off = WS_WU;  stride = 99; kmax = 99; nmax = 99;  }
    else if (frag < 120) { f = frag - 92;  src = W_v;  off = WS_WV;  stride = 99; kmax = 99; nmax = 99;  diag = 1; }
    else                 { f = frag - 120; src = W_r;  off = WS_WRB; stride = 99; kmax = 99; nmax = 99;  diag = 1; }
    int nt = f / 4, kc = f % 4;
    int n = nt * 16 + (lane & 15);
    u16* dst = wsu + off / 2 + ((long long)f * 64 + lane) * 8;
#pragma unroll
    for (int j = 0; j < 8; j++) {
      int k = kc * 32 + ((lane >> 4) << 3) + j;
      float v = 0.f;
      if (k < kmax && n < nmax && !(diag && k == n)) v = src[(long long)n * stride + k];
      dst[j] = cvt_bf16(v);
    }
  } else {
    // fp8 packs (x16)
    u8* ws8 = reinterpret_cast<u8*>(wsu);
    int frag = (blk - 38) * 4 + (threadIdx.x >> 6);
    const float* src; long long off; int KC, koff, kmax, nmax, stride, diag = 0, f;
    if (frag < 192)      { f = frag;       src = W_ih;   off = WS_WIHX8;  KC = 4; stride = 198; koff = 0; kmax = 99;  nmax = 768; }
    else if (frag < 576) { f = frag - 192; src = W_hh;   off = WS_WHH8;   KC = 8; stride = 256; koff = 0; kmax = 256; nmax = 768; }
    else if (frag < 632) { f = frag - 576; src = W_hist; off = WS_WHIST8; KC = 8; stride = 256; koff = 0; kmax = 256; nmax = 99;  }
    else if (frag < 660) { f = frag - 632; src = W_r;    off = WS_WR8;    KC = 4; stride = 99;  koff = 0; kmax = 99;  nmax = 99;  diag = 1; }
    else if (frag < 852) { f = frag - 660; src = W_ih;   off = WS_WIHM8;  KC = 4; stride = 198; koff = 99; kmax = 99; nmax = 768; }
    else return;
    int nt = f / KC, kc = f % KC;
    int n = nt * 16 + (lane & 15);
    u64 r = 0;
#pragma unroll
    for (int j = 0; j < 8; j++) {
      int k = kc * 32 + ((lane >> 4) << 3) + j;
      float v = 0.f;
      if (k < kmax && n < nmax && !(diag && k == n)) v = src[(long long)n * stride + koff + k] * 16.f;
      r |= (u64)enc_e4m3(v) << (8 * j);
    }
    *reinterpret_cast<u64*>(ws8 + off + ((long long)f * 64 + lane) * 8) = r;
  }
}

// ---------------- K2: parallel precompute ----------------
// grid 1600: one wave per (batch-chunk bc in [0,32), t). gim via fp8 MFMA (m is 0x50-coded fp8).
__global__ __launch_bounds__(256) void k2_pre(
    const float* __restrict__ x, const float* __restrict__ xh, const float* __restrict__ uu,
    const float* __restrict__ m, const float* __restrict__ dd,
    const float* __restrict__ b_td, const float* __restrict__ b_u, const float* __restrict__ b_v,
    const float* __restrict__ b_r, const float* __restrict__ b_ih,
    float* __restrict__ msum, float* __restrict__ out, u16* __restrict__ wsu) {
  const int tid = threadIdx.x, w = tid >> 6, lane = tid & 63;
  const int bc = blockIdx.x & 31, tg = blockIdx.x >> 5;
  const int t = tg * 4 + w;
  const int b0 = bc * 16;
  const int cl = lane & 15, rq = (lane >> 4) << 2, kr8 = (lane >> 4) << 3;
  const long long gb = (long long)(b0 + cl) * TV_ + (long long)t * V_;
  u8* ws8 = reinterpret_cast<u8*>(wsu);
  const u16* wtd = wsu + WS_WTD / 2;
  const u16* wu  = wsu + WS_WU / 2;
  const u16* wv  = wsu + WS_WV / 2;
  const u16* wrb = wsu + WS_WRB / 2;
  const u64* wm8 = reinterpret_cast<const u64*>(ws8 + WS_WIHM8);
  u16* gam = wsu + WS_GAMMA / 2;
  u16* xrp = wsu + WS_XRPRE / 2;
  u16* x16p = wsu + WS_X16 / 2;
  u16* xu16p = wsu + WS_XUS16 / 2;
  u8* m8p = ws8 + WS_M8;
  u8* gim8p = ws8 + WS_GIM8;
  const f32x4 z4 = {0.f, 0.f, 0.f, 0.f};
  constexpr float inv128 = 1.f / 128.f;

  // ---- gamma ----
  {
    s16x8 fd[4];
#pragma unroll
    for (int kc = 0; kc < 3; kc++) {
      int k0 = kc * 32 + kr8;
      fd[kc] = mk8(l4(dd + gb + k0), l4(dd + gb + k0 + 4));
    }
    {
      f32x4 a = z4;
      if (kr8 == 0) { a[0] = dd[gb + 96]; a[1] = dd[gb + 97]; a[2] = dd[gb + 98]; }
      fd[3] = mk8(a, z4);
    }
    for (int nt = 0; nt < 16; nt++) {
      int col = nt * 16 + cl;
      float bt = b_td[col];
      f32x4 a = {bt, bt, bt, bt};
#pragma unroll
      for (int kc = 0; kc < 4; kc++) a = mfma16(fd[kc], ldB(wtd, nt * 4 + kc, lane), a);
#pragma unroll
      for (int j = 0; j < 4; j++) {
        int b = b0 + rq + j;
        gam[((long long)t * B_ + b) * H_ + col] = cvt_bf16(__expf(-fmaxf(a[j], 0.f)));
      }
    }
  }

  // ---- gather pass: frags + x16 / m8 + fp8 m-frags ----
  s16x8 fu[4], fxb[4], fmx[4];
  u64 fm8[4];
  float mpart = 0.f;
  const long long rowoff = (long long)t * B_ + (b0 + cl);
  u16* x16row = x16p + rowoff * 100;
  u8* m8row = m8p + rowoff * 104;
#pragma unroll
  for (int kc = 0; kc < 3; kc++) {
    int k0 = kc * 32 + kr8;
    f32x4 u0 = l4(uu + gb + k0), u1 = l4(uu + gb + k0 + 4);
    f32x4 m0 = l4(m + gb + k0),  m1 = l4(m + gb + k0 + 4);
    f32x4 x0 = l4(x + gb + k0),  x1 = l4(x + gb + k0 + 4);
    f32x4 h0 = l4(xh + gb + k0), h1 = l4(xh + gb + k0 + 4);
    fu[kc]  = mk8(u0, u1);
    fmx[kc] = mk8(m0 * x0, m1 * x1);
    fxb[kc] = mk8(h0 + m0 * (x0 - h0), h1 + m1 * (x1 - h1));
    mpart += m0[0] + m0[1] + m0[2] + m0[3] + m1[0] + m1[1] + m1[2] + m1[3];
    u64 xw0 = (u64)pkbf(x0[0], x0[1]) | ((u64)pkbf(x0[2], x0[3]) << 32);
    u64 xw1 = (u64)pkbf(x1[0], x1[1]) | ((u64)pkbf(x1[2], x1[3]) << 32);
    *reinterpret_cast<u64*>(x16row + k0) = xw0;
    *reinterpret_cast<u64*>(x16row + k0 + 4) = xw1;
    u64 mb = 0;
#pragma unroll
    for (int e = 0; e < 4; e++) {
      mb |= (m0[e] > 0.5f ? 0x50ull : 0ull) << (8 * e);
      mb |= (m1[e] > 0.5f ? 0x50ull : 0ull) << (32 + 8 * e);
    }
    *reinterpret_cast<u64*>(m8row + k0) = mb;
    fm8[kc] = mb;
  }
  {
    f32x4 u0 = z4, m0 = z4, x0 = z4, h0 = z4;
    u64 mb = 0;
    if (kr8 == 0) {
#pragma unroll
      for (int e = 0; e < 3; e++) {
        u0[e] = uu[gb + 96 + e]; m0[e] = m[gb + 96 + e];
        x0[e] = x[gb + 96 + e];  h0[e] = xh[gb + 96 + e];
      }
#pragma unroll
      for (int e = 0; e < 3; e++) {
        x16row[96 + e] = cvt_bf16(x0[e]);
        m8row[96 + e] = (m0[e] > 0.5f) ? 0x50 : 0;
        mb |= (m0[e] > 0.5f ? 0x50ull : 0ull) << (8 * e);
      }
    }
    fu[3]  = mk8(u0, z4);
    fmx[3] = mk8(m0 * x0, z4);
    fxb[3] = mk8(h0 + m0 * (x0 - h0), z4);
    fm8[3] = mb;
    mpart += m0[0] + m0[1] + m0[2];
  }
  {
    float mp = mpart;
#pragma unroll
    for (int s = 32; s; s >>= 1) mp += __shfl_xor(mp, s);
    if (lane == 0) atomicAdd(&msum[t], mp);
  }

  // ---- V-wide GEMMs: unc / xu / xr_pre ----
  for (int nt = 0; nt < 7; nt++) {
    int col = nt * 16 + cl;
    float bu_ = 0.f, bv_ = 0.f, br_ = 0.f;
    if (col < V_) { bu_ = b_u[col]; bv_ = b_v[col]; br_ = b_r[col]; }
    f32x4 au = {bu_, bu_, bu_, bu_}, av = {bv_, bv_, bv_, bv_}, ar = {br_, br_, br_, br_};
#pragma unroll
    for (int kc = 0; kc < 4; kc++) {
      au = mfma16(fu[kc],  ldB(wu, nt * 4 + kc, lane), au);
      av = mfma16(fxb[kc], ldB(wv, nt * 4 + kc, lane), av);
      ar = mfma16(fmx[kc], ldB(wrb, nt * 4 + kc, lane), ar);
    }
    if (col < V_) {
#pragma unroll
      for (int j = 0; j < 4; j++) {
        int b = b0 + rq + j;
        float unc = __expf(-fmaxf(au[j], 0.f));
        float xuv = av[j] * unc;
        out[XUS_O + (long long)b * TV_ + (long long)t * V_ + col] = xuv;
        xu16p[((long long)t * B_ + b) * V_ + col] = cvt_bf16(xuv);
        xrp[((long long)t * B_ + b) * V_ + col] = cvt_bf16(ar[j]);
      }
    }
  }
  // ---- gim8 = fp8( (b_ih + m @ W_ihm) * 64 ), via fp8 MFMA (m x8, W x16 -> acc/128) ----
  for (int nt = 0; nt < 48; nt++) {
    int col = nt * 16 + cl;
    float bi = b_ih[col];
    f32x4 a = z4;
#pragma unroll
    for (int kc = 0; kc < 4; kc++)
      a = mfma8((i64)fm8[kc], (i64)wm8[(long long)(nt * 4 + kc) * 64 + lane], a);
    float g0 = (a[0] * inv128 + bi) * 64.f, g1 = (a[1] * inv128 + bi) * 64.f;
    float g2 = (a[2] * inv128 + bi) * 64.f, g3 = (a[3] * inv128 + bi) * 64.f;
    u32 p = cvtfp8x2(g0, g1) | (cvtfp8x2(g2, g3) << 16);
    *reinterpret_cast<u32*>(gim8p + (((long long)t * 32 + bc) * 48 + nt) * 256 + (long long)lane * 4) = p;
  }
}

// ---------------- K_SEQ: persistent scan; 128 WGs x 4 rows x 1024 threads ----------------
// R9-proven structure (__syncthreads barriers) + 1-step-ahead gim register prefetch.
__global__ void __attribute__((amdgpu_flat_work_group_size(1024, 1024), amdgpu_waves_per_eu(4, 4)))
k_seq(
    const float* __restrict__ b_hist, const float* __restrict__ b_hh,
    const float* __restrict__ conv_w, const float* __restrict__ conv_b,
    const float* __restrict__ W_fc, const float* __restrict__ b_fc,
    const float* __restrict__ msum, float* out, u16* wsu) {
  __shared__ __align__(16) u8 hp8_s[16 * 272];
  __shared__ __align__(16) u8 e8_s[16 * 144];
  __shared__ __align__(16) u8 xi8_s[16 * 144];
  __shared__ __align__(16) u8 whhR_l[65536];
  __shared__ __align__(16) u8 whist8_l[28672];
  __shared__ __align__(16) u8 wr8_l[14336];
  __shared__ __align__(16) float hf_s[4][260];
  __shared__ float red_s[1024];

  const int tid = threadIdx.x, wv = tid >> 6, lane = tid & 63;
  const int cl = lane & 15, rq = (lane >> 4) << 2, kr8 = (lane >> 4) << 3;
  const int b0 = blockIdx.x * 4;
  const int cc = blockIdx.x >> 2, quarter = blockIdx.x & 3;
  const u8* ws8 = reinterpret_cast<const u8*>(wsu);

  for (int i = tid; i < 1088; i += 1024) reinterpret_cast<u32*>(hp8_s)[i] = 0;
  for (int i = tid; i < 576; i += 1024) { reinterpret_cast<u32*>(e8_s)[i] = 0; reinterpret_cast<u32*>(xi8_s)[i] = 0; }
  {
    const u32* s0 = reinterpret_cast<const u32*>(ws8 + WS_WHH8);
    u32* d0 = reinterpret_cast<u32*>(whhR_l);
    for (int i = tid; i < 16384; i += 1024) d0[i] = s0[i];
    const u32* s1 = reinterpret_cast<const u32*>(ws8 + WS_WHIST8);
    u32* d1 = reinterpret_cast<u32*>(whist8_l);
    for (int i = tid; i < 7168; i += 1024) d1[i] = s1[i];
    const u32* s2 = reinterpret_cast<const u32*>(ws8 + WS_WR8);
    u32* d2 = reinterpret_cast<u32*>(wr8_l);
    for (int i = tid; i < 3584; i += 1024) d2[i] = s2[i];
  }

  // resident fp8 weights: wihx (3 gates) + whh z,n
  const u64* wx8 = reinterpret_cast<const u64*>(ws8 + WS_WIHX8);
  const u64* wh8 = reinterpret_cast<const u64*>(ws8 + WS_WHH8);
  i64 wihx_r[3][4];
  i64 whhZ[8], whhN[8];
#pragma unroll
  for (int gg = 0; gg < 3; gg++)
#pragma unroll
    for (int kc = 0; kc < 4; kc++)
      wihx_r[gg][kc] = (i64)wx8[(long long)((gg * 16 + wv) * 4 + kc) * 64 + lane];
#pragma unroll
  for (int kc = 0; kc < 8; kc++) {
    whhZ[kc] = (i64)wh8[(long long)((16 + wv) * 8 + kc) * 64 + lane];
    whhN[kc] = (i64)wh8[(long long)((32 + wv) * 8 + kc) * 64 + lane];
  }

  const int col = wv * 16 + cl;
  const float bhh0 = b_hh[col], bhh1 = b_hh[256 + col], bhh2 = b_hh[512 + col];
  const bool rowok = (rq < 4);
  const bool vwave = (wv < 7);
  const int vcol = col;
  const bool vact = vwave && (vcol < V_);
  const bool vld = vact && rowok;
  const float bh = vact ? b_hist[vcol] : 0.f;
  const float cw0 = conv_w[0], cw1 = conv_w[1], cb = conv_b[0];

  const u16* gamp = wsu + WS_GAMMA / 2;
  const u16* x16p = wsu + WS_X16 / 2;
  const u16* xu16p = wsu + WS_XUS16 / 2;
  const u16* xrpp = wsu + WS_XRPRE / 2;
  const u8* m8p = ws8 + WS_M8;
  int lane_p = ((quarter + (rq >> 2)) * 16 + cl) & 63;
  const u8* gimp = ws8 + WS_GIM8 + (((long long)cc * 48 + wv) * 64 + lane_p) * 4;

  u32 gaidx = BH_ + (u32)(b0 + rq) * H_ + col;
  u32 xidx = (u32)(b0 + rq) * 100 + vcol;
  u32 xuidx = (u32)(b0 + rq) * 99 + vcol;
  u32 midx = (u32)(b0 + rq) * 104 + vcol;
  u32 gidx = (u32)(b0 + rq) * TV_ + vcol;

  float hpr[4] = {0.f, 0.f, 0.f, 0.f};
  float loss_acc = 0.f;
  constexpr float inv128 = 1.f / 128.f;
  constexpr float inv64 = 1.f / 64.f;
  const f32x4 z4 = {0.f, 0.f, 0.f, 0.f};

  // preload gim for t=0 (drains at first barrier; one-time cost)
  u32 gimC0, gimC1, gimC2;
  {
    const u32* gp = reinterpret_cast<const u32*>(gimp);
    gimC0 = gp[0]; gimC1 = gp[1024]; gimC2 = gp[2048];
  }
  __syncthreads();

  for (int t = 0; t < T_; t++) {
    // ---- step-top: issue all global loads (gim for t+1 -> full-step latency cover) ----
    u32 gimN0 = 0, gimN1 = 0, gimN2 = 0;
    if (t + 1 < T_) {
      const u32* gp = reinterpret_cast<const u32*>(gimp + (long long)(t + 1) * 393216);
      gimN0 = gp[0]; gimN1 = gp[1024]; gimN2 = gp[2048];
    }
    u16 ga[4] = {0, 0, 0, 0};
    if (rowok && t + 1 < T_) {
#pragma unroll
      for (int j = 0; j < 4; j++) ga[j] = gamp[gaidx + (u32)j * H_];
    }
    gaidx += BH_;
    u16 cx16[4] = {0, 0, 0, 0}, cxu[4] = {0, 0, 0, 0}, cxr[4] = {0, 0, 0, 0};
    u8 cm8[4] = {0, 0, 0, 0};
    if (vld) {
#pragma unroll
      for (int j = 0; j < 4; j++) {
        cx16[j] = x16p[xidx + (u32)j * 100];
        cxu[j]  = xu16p[xuidx + (u32)j * 99];
        cxr[j]  = xrpp[xuidx + (u32)j * 99];
        cm8[j]  = m8p[midx + (u32)j * 104];
      }
    }
    xidx += B_ * 100; xuidx += B_ * 99; midx += B_ * 104;
    const float msv = msum[t];

    // ---- P1: gh chains + x_h ----
    f32x4 accR = z4, accZ = z4, accNh = z4, accXh = z4;
#pragma unroll
    for (int kc = 0; kc < 8; kc++) {
      const i64 a = *reinterpret_cast<const i64*>(&hp8_s[cl * 272 + kc * 32 + kr8]);
      const i64 br = *reinterpret_cast<const i64*>(&whhR_l[(wv * 8 + kc) * 512 + lane * 8]);
      accR  = mfma8(a, br, accR);
      accZ  = mfma8(a, whhZ[kc], accZ);
      accNh = mfma8(a, whhN[kc], accNh);
      if (vwave) {
        const i64 bw = *reinterpret_cast<const i64*>(&whist8_l[(wv * 8 + kc) * 512 + lane * 8]);
        accXh = mfma8(a, bw, accXh);
      }
    }
    if (vld) {
#pragma unroll
      for (int j = 0; j < 4; j++) {
        const float xhv = accXh[j] * inv128 + bh;
        const float ev = cm8[j] ? 0.f : xhv;
        e8_s[(rq + j) * 144 + vcol] = (u8)cvtfp8(ev * 8.f);
      }
    }
    __syncthreads();

    // ---- P2: xr, x_comb, loss, x_imp, xrs ----
    if (vwave) {
      f32x4 acc = z4;
#pragma unroll
      for (int kc = 0; kc < 4; kc++) {
        const i64 a = *reinterpret_cast<const i64*>(&e8_s[cl * 144 + kc * 32 + kr8]);
        const i64 b = *reinterpret_cast<const i64*>(&wr8_l[(wv * 4 + kc) * 512 + lane * 8]);
        acc = mfma8(a, b, acc);
      }
      if (vld) {
        const float inv_ms = 1.f / (msv + 1e-5f);
        float ls = 0.f;
#pragma unroll
        for (int j = 0; j < 4; j++) {
          const float xrv = acc[j] * inv128 + cvt_f32(cxr[j]);
          const float xc = cw0 * cvt_f32(cxu[j]) + cw1 * xrv + cb;
          const float xj = cvt_f32(cx16[j]);
          const bool mj = cm8[j] != 0;
          const float ximp = mj ? xj : xc;
          ls += mj ? fabsf(xj - xc) : 0.f;
          const u32 gj = gidx + (u32)j * TV_;
          out[XIMP_O + gj] = ximp;
          out[XRS_O + gj] = xrv;
          xi8_s[(rq + j) * 144 + vcol] = (u8)cvtfp8(ximp * 8.f);
        }
        loss_acc += ls * inv_ms;
      }
    }
    gidx += V_;
    __syncthreads();

    // ---- P3: gi x-part + GRU update (+ fused gamma[t+1]) ----
    f32x4 accNx = z4;
#pragma unroll
    for (int kc = 0; kc < 4; kc++) {
      const i64 a = *reinterpret_cast<const i64*>(&xi8_s[cl * 144 + kc * 32 + kr8]);
      accR  = mfma8(a, wihx_r[0][kc], accR);
      accZ  = mfma8(a, wihx_r[1][kc], accZ);
      accNx = mfma8(a, wihx_r[2][kc], accNx);
    }
    const f32x4 gimR = dec8x4(gimC0);
    const f32x4 gimZ = dec8x4(gimC1);
    const f32x4 gimN = dec8x4(gimC2);
#pragma unroll
    for (int j = 0; j < 4; j++) {
      const float rr = sigm(accR[j] * inv128 + gimR[j] * inv64 + bhh0);
      const float zz = sigm(accZ[j] * inv128 + gimZ[j] * inv64 + bhh1);
      const float gin = accNx[j] * inv128 + gimN[j] * inv64;
      const float ghn = accNh[j] * inv128 + bhh2;
      const float nn = tanhx(gin + rr * ghn);
      const float hn = (1.f - zz) * nn + zz * hpr[j];
      if (t + 1 < T_) {
        const float hpnew = hn * cvt_f32(ga[j]);
        hpr[j] = hpnew;
        if (rowok) hp8_s[(rq + j) * 272 + col] = (u8)cvtfp8(hpnew * 8.f);
      } else {
        if (rowok) hf_s[rq + j][col] = hn;
      }
    }
    // rotate gim prefetch
    gimC0 = gimN0; gimC1 = gimN1; gimC2 = gimN2;
    __syncthreads();
  }

  // ---- epilogue ----
  if (tid < 4) {
    float acc = 0.f;
    for (int k = 0; k < H_; k++) acc += hf_s[tid][k] * W_fc[k];
    const float yv = acc + b_fc[0];
    out[YOUT_O + b0 + tid] = yv;
    out[YSC_O + b0 + tid] = 1.f / (1.f + __expf(-yv));
  }
  red_s[tid] = loss_acc;
  __syncthreads();
  for (int s = 512; s; s >>= 1) {
    if (tid < s) red_s[tid] += red_s[tid + s];
    __syncthreads();
  }
  if (tid == 0) {
    float* lp = reinterpret_cast<float*>(reinterpret_cast<char*>(wsu) + WS_LOSSP);
    lp[blockIdx.x] = red_s[0];
  }
}

// ---------------- K3: deterministic loss reduction ----------------
__global__ void k3_loss(const float* __restrict__ lossp, float* __restrict__ out) {
  if (threadIdx.x == 0) {
    float s = 0.f;
    for (int i = 0; i < 128; i++) s += lossp[i];
    out[LOSS_O] = s;
  }
}

extern "C" void kernel_launch(void* const* d_in, const int* in_sizes, int n_in,
                              void* d_out, int out_size, void* d_ws, size_t ws_size,
                              hipStream_t stream) {
  (void)in_sizes; (void)n_in; (void)out_size; (void)ws_size;
  const float* x      = (const float*)d_in[0];
  const float* xhat   = (const float*)d_in[1];
  const float* u      = (const float*)d_in[2];
  const float* m      = (const float*)d_in[3];
  const float* d      = (const float*)d_in[4];
  const float* W_td   = (const float*)d_in[6];
  const float* b_td   = (const float*)d_in[7];
  const float* W_hist = (const float*)d_in[8];
  const float* b_hist = (const float*)d_in[9];
  const float* W_v    = (const float*)d_in[10];
  const float* b_v    = (const float*)d_in[11];
  const float* W_r    = (const float*)d_in[12];
  const float* b_r    = (const float*)d_in[13];
  const float* W_u    = (const float*)d_in[14];
  const float* b_u    = (const float*)d_in[15];
  const float* conv_w = (const float*)d_in[16];
  const float* conv_b = (const float*)d_in[17];
  const float* W_ih   = (const float*)d_in[18];
  const float* b_ih   = (const float*)d_in[19];
  const float* W_hh   = (const float*)d_in[20];
  const float* b_hh   = (const float*)d_in[21];
  const float* W_fc   = (const float*)d_in[22];
  const float* b_fc   = (const float*)d_in[23];
  float* out = (float*)d_out;
  u16* wsu = (u16*)d_ws;
  float* msum = (float*)d_ws;
  const float* lossp = (const float*)((char*)d_ws + WS_LOSSP);

  hipLaunchKernelGGL(k0_all, dim3(251), dim3(256), 0, stream,
                     W_td, W_u, W_v, W_r, W_ih, W_hh, W_hist, msum, wsu);
  hipLaunchKernelGGL(k2_pre, dim3(1600), dim3(256), 0, stream,
                     x, xhat, u, m, d, b_td, b_u, b_v, b_r, b_ih, msum, out, wsu);
  hipLaunchKernelGGL(k_seq, dim3(128), dim3(1024), 0, stream,
                     b_hist, b_hh, conv_w, conv_b, W_fc, b_fc, msum, out, wsu);
  hipLaunchKernelGGL(k3_loss, dim3(1), dim3(64), 0, stream, lossp, out);
}

// Round 12
// 1259.127 us; speedup vs baseline: 1.1069x; 1.0260x over previous
//
#include <hip/hip_runtime.h>

typedef unsigned short u16;
typedef unsigned int   u32;
typedef unsigned char  u8;
typedef unsigned long long u64;
typedef long i64;
typedef __attribute__((ext_vector_type(8))) short s16x8;
typedef __attribute__((ext_vector_type(4))) float f32x4;
typedef __attribute__((ext_vector_type(2))) float f32x2;
typedef __attribute__((ext_vector_type(4), aligned(4))) float f32x4u;

#define DEV static __device__ __forceinline__

constexpr int B_ = 512, T_ = 200, V_ = 99, H_ = 256;
constexpr int TV_ = T_ * V_;
constexpr u32 BH_ = B_ * H_;

// d_out f32 element offsets: (x_imp, y_out, y_score, x_loss, xus, xrs)
constexpr long long XIMP_O = 0;
constexpr long long YOUT_O = 10137600;
constexpr long long YSC_O  = 10138112;
constexpr long long LOSS_O = 10138624;
constexpr long long XUS_O  = 10138625;
constexpr long long XRS_O  = 20276225;

// ---- workspace byte offsets ----
constexpr long long WS_MSUM   = 0;                          // 200 f32
constexpr long long WS_GAMMA  = 1024;                       // [T][B][H] bf16
constexpr long long WS_XRPRE  = 52429824;                   // [T][B][99] bf16
constexpr long long WS_X16    = 72705024;                   // [T][B][100] bf16
constexpr long long WS_XUS16  = 93185024;                   // [T][B][99] bf16
constexpr long long WS_M8     = 113460224;                  // [T][B][104] u8
constexpr long long WS_GIM8   = 124109824;                  // [T][32][48][64][4] u8 (78,643,200)
constexpr long long WS_WTD    = 202753024;                  // bf16 packs (k2)
constexpr long long WS_WU     = WS_WTD + 65536;
constexpr long long WS_WV     = WS_WU + 28672;
constexpr long long WS_WRB    = WS_WV + 28672;
constexpr long long WS_F8     = WS_WRB + 28672;             // fp8 packs
constexpr long long WS_WIHX8  = WS_F8;                      // 96KB
constexpr long long WS_WHH8   = WS_F8 + 98304;              // 192KB
constexpr long long WS_WHIST8 = WS_F8 + 294912;             // 28KB
constexpr long long WS_WR8    = WS_F8 + 323584;             // 14KB
constexpr long long WS_WIHM8  = WS_F8 + 337920;             // 96KB (m-part of W_ih, fp8)
constexpr long long WS_LOSSP  = WS_F8 + 436224;             // 128 f32

DEV u16 cvt_bf16(float f) {
  union { float f; u32 u; } v; v.f = f;
  u32 u = v.u;
  return (u16)((u + 0x7fffu + ((u >> 16) & 1u)) >> 16);
}
DEV float cvt_f32(u16 h) {
  union { u32 u; float f; } v; v.u = ((u32)h) << 16;
  return v.f;
}
DEV u32 enc_e4m3(float f) {
  union { float f; u32 u; } v; v.f = f;
  u32 sign = (v.u >> 24) & 0x80u;
  v.u &= 0x7fffffffu;
  float a = fminf(v.f, 448.f);
  if (a < 0.015625f) {
    int mq = (int)rintf(a * 512.f);
    return sign | (u32)mq;
  }
  union { float f; u32 u; } w; w.f = a;
  u32 lsb = (w.u >> 20) & 1u;
  u32 r = w.u + 0x7FFFFu + lsb;
  u32 E = ((r >> 23) & 0xffu) - 120u;
  u32 M = (r >> 20) & 7u;
  if (E >= 16u) { E = 15u; M = 6u; }
  return sign | (E << 3) | M;
}
DEV u32 cvtfp8(float a) {
  u32 r;
  asm("v_cvt_pk_fp8_f32 %0, %1, %2" : "=v"(r) : "v"(a), "v"(a));
  return r;
}
DEV u32 cvtfp8x2(float a, float b) {
  u32 r;
  asm("v_cvt_pk_fp8_f32 %0, %1, %2" : "=v"(r) : "v"(a), "v"(b));
  return r & 0xffffu;
}
DEV u32 pkbf(float a, float b) {
  u32 r;
  asm("v_cvt_pk_bf16_f32 %0, %1, %2" : "=v"(r) : "v"(a), "v"(b));
  return r;
}
#if __has_builtin(__builtin_amdgcn_cvt_pk_f32_fp8)
DEV f32x4 dec8x4(u32 w) {
  f32x2 lo = __builtin_amdgcn_cvt_pk_f32_fp8((int)w, false);
  f32x2 hi = __builtin_amdgcn_cvt_pk_f32_fp8((int)w, true);
  return (f32x4){lo[0], lo[1], hi[0], hi[1]};
}
#else
DEV float dec8(u32 b) {
  u32 e = (b >> 3) & 0xfu, mm = b & 7u, s = b >> 7;
  union { u32 u; float f; } v;
  v.u = (s << 31) | ((e + 120u) << 23) | (mm << 20);
  return e ? v.f : 0.f;
}
DEV f32x4 dec8x4(u32 w) {
  return (f32x4){dec8(w & 0xff), dec8((w >> 8) & 0xff), dec8((w >> 16) & 0xff), dec8(w >> 24)};
}
#endif
DEV s16x8 mk8(f32x4 lo, f32x4 hi) {
  union { u32 q[4]; s16x8 v; } u;
  u.q[0] = pkbf(lo[0], lo[1]); u.q[1] = pkbf(lo[2], lo[3]);
  u.q[2] = pkbf(hi[0], hi[1]); u.q[3] = pkbf(hi[2], hi[3]);
  return u.v;
}
DEV f32x4 l4(const float* p) { return (f32x4)(*(const f32x4u*)p); }
DEV f32x4 mfma16(s16x8 a, s16x8 b, f32x4 c) {
  return __builtin_amdgcn_mfma_f32_16x16x32_bf16(a, b, c, 0, 0, 0);
}
DEV f32x4 mfma8(i64 a, i64 b, f32x4 c) {
  return __builtin_amdgcn_mfma_f32_16x16x32_fp8_fp8(a, b, c, 0, 0, 0);
}
DEV s16x8 ldB(const u16* w, int frag, int lane) {
  return *reinterpret_cast<const s16x8*>(w + ((long long)frag * 64 + lane) * 8);
}
DEV float sigm(float v) { return 1.f / (1.f + __expf(-v)); }
DEV float tanhx(float v) {
  float e = __expf(-2.f * fabsf(v));
  float t = (1.f - e) / (1.f + e);
  return v < 0.f ? -t : t;
}

// ---------------- K0: merged pack (bf16 + fp8 fragments); zero msum ----------------
// blocks 0-36: bf16 frags 0-147 | block 37: msum zero | blocks 38-250: fp8 frags 0-851
__global__ __launch_bounds__(256) void k0_all(
    const float* __restrict__ W_td, const float* __restrict__ W_u, const float* __restrict__ W_v,
    const float* __restrict__ W_r, const float* __restrict__ W_ih, const float* __restrict__ W_hh,
    const float* __restrict__ W_hist,
    float* __restrict__ msum, u16* __restrict__ wsu) {
  const int blk = blockIdx.x;
  if (blk == 37) {
    if (threadIdx.x < T_) msum[threadIdx.x] = 0.f;
    return;
  }
  const int lane = threadIdx.x & 63;
  if (blk < 37) {
    // bf16 packs for k2
    int frag = blk * 4 + (threadIdx.x >> 6);
    const float* src; long long off; int kmax, nmax, stride, diag = 0, f;
    if (frag < 64)       { f = frag;       src = W_td; off = WS_WTD; stride = 99; kmax = 99; nmax = 256; }
    else if (frag < 92)  { f = frag - 64;  src = W_u;  off = WS_WU;  stride = 99; kmax = 99; nmax = 99;  }
    else if (frag < 120) { f = frag - 92;  src = W_v;  off = WS_WV;  stride = 99; kmax = 99; nmax = 99;  diag = 1; }
    else                 { f = frag - 120; src = W_r;  off = WS_WRB; stride = 99; kmax = 99; nmax = 99;  diag = 1; }
    int nt = f / 4, kc = f % 4;
    int n = nt * 16 + (lane & 15);
    u16* dst = wsu + off / 2 + ((long long)f * 64 + lane) * 8;
#pragma unroll
    for (int j = 0; j < 8; j++) {
      int k = kc * 32 + ((lane >> 4) << 3) + j;
      float v = 0.f;
      if (k < kmax && n < nmax && !(diag && k == n)) v = src[(long long)n * stride + k];
      dst[j] = cvt_bf16(v);
    }
  } else {
    // fp8 packs (x16)
    u8* ws8 = reinterpret_cast<u8*>(wsu);
    int frag = (blk - 38) * 4 + (threadIdx.x >> 6);
    const float* src; long long off; int KC, koff, kmax, nmax, stride, diag = 0, f;
    if (frag < 192)      { f = frag;       src = W_ih;   off = WS_WIHX8;  KC = 4; stride = 198; koff = 0; kmax = 99;  nmax = 768; }
    else if (frag < 576) { f = frag - 192; src = W_hh;   off = WS_WHH8;   KC = 8; stride = 256; koff = 0; kmax = 256; nmax = 768; }
    else if (frag < 632) { f = frag - 576; src = W_hist; off = WS_WHIST8; KC = 8; stride = 256; koff = 0; kmax = 256; nmax = 99;  }
    else if (frag < 660) { f = frag - 632; src = W_r;    off = WS_WR8;    KC = 4; stride = 99;  koff = 0; kmax = 99;  nmax = 99;  diag = 1; }
    else if (frag < 852) { f = frag - 660; src = W_ih;   off = WS_WIHM8;  KC = 4; stride = 198; koff = 99; kmax = 99; nmax = 768; }
    else return;
    int nt = f / KC, kc = f % KC;
    int n = nt * 16 + (lane & 15);
    u64 r = 0;
#pragma unroll
    for (int j = 0; j < 8; j++) {
      int k = kc * 32 + ((lane >> 4) << 3) + j;
      float v = 0.f;
      if (k < kmax && n < nmax && !(diag && k == n)) v = src[(long long)n * stride + koff + k] * 16.f;
      r |= (u64)enc_e4m3(v) << (8 * j);
    }
    *reinterpret_cast<u64*>(ws8 + off + ((long long)f * 64 + lane) * 8) = r;
  }
}

// ---------------- K2: parallel precompute ----------------
// grid 1600: one wave per (batch-chunk bc in [0,32), t). gim via fp8 MFMA (m is 0x50-coded fp8).
__global__ __launch_bounds__(256) void k2_pre(
    const float* __restrict__ x, const float* __restrict__ xh, const float* __restrict__ uu,
    const float* __restrict__ m, const float* __restrict__ dd,
    const float* __restrict__ b_td, const float* __restrict__ b_u, const float* __restrict__ b_v,
    const float* __restrict__ b_r, const float* __restrict__ b_ih,
    float* __restrict__ msum, float* __restrict__ out, u16* __restrict__ wsu) {
  const int tid = threadIdx.x, w = tid >> 6, lane = tid & 63;
  const int bc = blockIdx.x & 31, tg = blockIdx.x >> 5;
  const int t = tg * 4 + w;
  const int b0 = bc * 16;
  const int cl = lane & 15, rq = (lane >> 4) << 2, kr8 = (lane >> 4) << 3;
  const long long gb = (long long)(b0 + cl) * TV_ + (long long)t * V_;
  u8* ws8 = reinterpret_cast<u8*>(wsu);
  const u16* wtd = wsu + WS_WTD / 2;
  const u16* wu  = wsu + WS_WU / 2;
  const u16* wv  = wsu + WS_WV / 2;
  const u16* wrb = wsu + WS_WRB / 2;
  const u64* wm8 = reinterpret_cast<const u64*>(ws8 + WS_WIHM8);
  u16* gam = wsu + WS_GAMMA / 2;
  u16* xrp = wsu + WS_XRPRE / 2;
  u16* x16p = wsu + WS_X16 / 2;
  u16* xu16p = wsu + WS_XUS16 / 2;
  u8* m8p = ws8 + WS_M8;
  u8* gim8p = ws8 + WS_GIM8;
  const f32x4 z4 = {0.f, 0.f, 0.f, 0.f};
  constexpr float inv128 = 1.f / 128.f;

  // ---- gamma ----
  {
    s16x8 fd[4];
#pragma unroll
    for (int kc = 0; kc < 3; kc++) {
      int k0 = kc * 32 + kr8;
      fd[kc] = mk8(l4(dd + gb + k0), l4(dd + gb + k0 + 4));
    }
    {
      f32x4 a = z4;
      if (kr8 == 0) { a[0] = dd[gb + 96]; a[1] = dd[gb + 97]; a[2] = dd[gb + 98]; }
      fd[3] = mk8(a, z4);
    }
    for (int nt = 0; nt < 16; nt++) {
      int col = nt * 16 + cl;
      float bt = b_td[col];
      f32x4 a = {bt, bt, bt, bt};
#pragma unroll
      for (int kc = 0; kc < 4; kc++) a = mfma16(fd[kc], ldB(wtd, nt * 4 + kc, lane), a);
#pragma unroll
      for (int j = 0; j < 4; j++) {
        int b = b0 + rq + j;
        gam[((long long)t * B_ + b) * H_ + col] = cvt_bf16(__expf(-fmaxf(a[j], 0.f)));
      }
    }
  }

  // ---- gather pass: frags + x16 / m8 + fp8 m-frags ----
  s16x8 fu[4], fxb[4], fmx[4];
  u64 fm8[4];
  float mpart = 0.f;
  const long long rowoff = (long long)t * B_ + (b0 + cl);
  u16* x16row = x16p + rowoff * 100;
  u8* m8row = m8p + rowoff * 104;
#pragma unroll
  for (int kc = 0; kc < 3; kc++) {
    int k0 = kc * 32 + kr8;
    f32x4 u0 = l4(uu + gb + k0), u1 = l4(uu + gb + k0 + 4);
    f32x4 m0 = l4(m + gb + k0),  m1 = l4(m + gb + k0 + 4);
    f32x4 x0 = l4(x + gb + k0),  x1 = l4(x + gb + k0 + 4);
    f32x4 h0 = l4(xh + gb + k0), h1 = l4(xh + gb + k0 + 4);
    fu[kc]  = mk8(u0, u1);
    fmx[kc] = mk8(m0 * x0, m1 * x1);
    fxb[kc] = mk8(h0 + m0 * (x0 - h0), h1 + m1 * (x1 - h1));
    mpart += m0[0] + m0[1] + m0[2] + m0[3] + m1[0] + m1[1] + m1[2] + m1[3];
    u64 xw0 = (u64)pkbf(x0[0], x0[1]) | ((u64)pkbf(x0[2], x0[3]) << 32);
    u64 xw1 = (u64)pkbf(x1[0], x1[1]) | ((u64)pkbf(x1[2], x1[3]) << 32);
    *reinterpret_cast<u64*>(x16row + k0) = xw0;
    *reinterpret_cast<u64*>(x16row + k0 + 4) = xw1;
    u64 mb = 0;
#pragma unroll
    for (int e = 0; e < 4; e++) {
      mb |= (m0[e] > 0.5f ? 0x50ull : 0ull) << (8 * e);
      mb |= (m1[e] > 0.5f ? 0x50ull : 0ull) << (32 + 8 * e);
    }
    *reinterpret_cast<u64*>(m8row + k0) = mb;
    fm8[kc] = mb;
  }
  {
    f32x4 u0 = z4, m0 = z4, x0 = z4, h0 = z4;
    u64 mb = 0;
    if (kr8 == 0) {
#pragma unroll
      for (int e = 0; e < 3; e++) {
        u0[e] = uu[gb + 96 + e]; m0[e] = m[gb + 96 + e];
        x0[e] = x[gb + 96 + e];  h0[e] = xh[gb + 96 + e];
      }
#pragma unroll
      for (int e = 0; e < 3; e++) {
        x16row[96 + e] = cvt_bf16(x0[e]);
        m8row[96 + e] = (m0[e] > 0.5f) ? 0x50 : 0;
        mb |= (m0[e] > 0.5f ? 0x50ull : 0ull) << (8 * e);
      }
    }
    fu[3]  = mk8(u0, z4);
    fmx[3] = mk8(m0 * x0, z4);
    fxb[3] = mk8(h0 + m0 * (x0 - h0), z4);
    fm8[3] = mb;
    mpart += m0[0] + m0[1] + m0[2];
  }
  {
    float mp = mpart;
#pragma unroll
    for (int s = 32; s; s >>= 1) mp += __shfl_xor(mp, s);
    if (lane == 0) atomicAdd(&msum[t], mp);
  }

  // ---- V-wide GEMMs: unc / xu / xr_pre ----
  for (int nt = 0; nt < 7; nt++) {
    int col = nt * 16 + cl;
    float bu_ = 0.f, bv_ = 0.f, br_ = 0.f;
    if (col < V_) { bu_ = b_u[col]; bv_ = b_v[col]; br_ = b_r[col]; }
    f32x4 au = {bu_, bu_, bu_, bu_}, av = {bv_, bv_, bv_, bv_}, ar = {br_, br_, br_, br_};
#pragma unroll
    for (int kc = 0; kc < 4; kc++) {
      au = mfma16(fu[kc],  ldB(wu, nt * 4 + kc, lane), au);
      av = mfma16(fxb[kc], ldB(wv, nt * 4 + kc, lane), av);
      ar = mfma16(fmx[kc], ldB(wrb, nt * 4 + kc, lane), ar);
    }
    if (col < V_) {
#pragma unroll
      for (int j = 0; j < 4; j++) {
        int b = b0 + rq + j;
        float unc = __expf(-fmaxf(au[j], 0.f));
        float xuv = av[j] * unc;
        out[XUS_O + (long long)b * TV_ + (long long)t * V_ + col] = xuv;
        xu16p[((long long)t * B_ + b) * V_ + col] = cvt_bf16(xuv);
        xrp[((long long)t * B_ + b) * V_ + col] = cvt_bf16(ar[j]);
      }
    }
  }
  // ---- gim8 = fp8( (b_ih + m @ W_ihm) * 64 ), via fp8 MFMA (m x8, W x16 -> acc/128) ----
  for (int nt = 0; nt < 48; nt++) {
    int col = nt * 16 + cl;
    float bi = b_ih[col];
    f32x4 a = z4;
#pragma unroll
    for (int kc = 0; kc < 4; kc++)
      a = mfma8((i64)fm8[kc], (i64)wm8[(long long)(nt * 4 + kc) * 64 + lane], a);
    float g0 = (a[0] * inv128 + bi) * 64.f, g1 = (a[1] * inv128 + bi) * 64.f;
    float g2 = (a[2] * inv128 + bi) * 64.f, g3 = (a[3] * inv128 + bi) * 64.f;
    u32 p = cvtfp8x2(g0, g1) | (cvtfp8x2(g2, g3) << 16);
    *reinterpret_cast<u32*>(gim8p + (((long long)t * 32 + bc) * 48 + nt) * 256 + (long long)lane * 4) = p;
  }
}

// ---------------- K_SEQ: persistent scan; 128 WGs x 4 rows x 1024 threads (exact R9) ----------------
__global__ void __attribute__((amdgpu_flat_work_group_size(1024, 1024), amdgpu_waves_per_eu(4, 4)))
k_seq(
    const float* __restrict__ b_hist, const float* __restrict__ b_hh,
    const float* __restrict__ conv_w, const float* __restrict__ conv_b,
    const float* __restrict__ W_fc, const float* __restrict__ b_fc,
    const float* __restrict__ msum, float* out, u16* wsu) {
  __shared__ __align__(16) u8 hp8_s[16 * 272];
  __shared__ __align__(16) u8 e8_s[16 * 144];
  __shared__ __align__(16) u8 xi8_s[16 * 144];
  __shared__ __align__(16) u8 whhR_l[65536];
  __shared__ __align__(16) u8 whist8_l[28672];
  __shared__ __align__(16) u8 wr8_l[14336];
  __shared__ __align__(16) float hf_s[4][260];
  __shared__ float red_s[1024];

  const int tid = threadIdx.x, wv = tid >> 6, lane = tid & 63;
  const int cl = lane & 15, rq = (lane >> 4) << 2, kr8 = (lane >> 4) << 3;
  const int b0 = blockIdx.x * 4;
  const int cc = blockIdx.x >> 2, quarter = blockIdx.x & 3;
  const u8* ws8 = reinterpret_cast<const u8*>(wsu);

  for (int i = tid; i < 1088; i += 1024) reinterpret_cast<u32*>(hp8_s)[i] = 0;
  for (int i = tid; i < 576; i += 1024) { reinterpret_cast<u32*>(e8_s)[i] = 0; reinterpret_cast<u32*>(xi8_s)[i] = 0; }
  {
    const u32* s0 = reinterpret_cast<const u32*>(ws8 + WS_WHH8);
    u32* d0 = reinterpret_cast<u32*>(whhR_l);
    for (int i = tid; i < 16384; i += 1024) d0[i] = s0[i];
    const u32* s1 = reinterpret_cast<const u32*>(ws8 + WS_WHIST8);
    u32* d1 = reinterpret_cast<u32*>(whist8_l);
    for (int i = tid; i < 7168; i += 1024) d1[i] = s1[i];
    const u32* s2 = reinterpret_cast<const u32*>(ws8 + WS_WR8);
    u32* d2 = reinterpret_cast<u32*>(wr8_l);
    for (int i = tid; i < 3584; i += 1024) d2[i] = s2[i];
  }

  // resident fp8 weights: wihx (3 gates) + whh z,n
  const u64* wx8 = reinterpret_cast<const u64*>(ws8 + WS_WIHX8);
  const u64* wh8 = reinterpret_cast<const u64*>(ws8 + WS_WHH8);
  i64 wihx_r[3][4];
  i64 whhZ[8], whhN[8];
#pragma unroll
  for (int gg = 0; gg < 3; gg++)
#pragma unroll
    for (int kc = 0; kc < 4; kc++)
      wihx_r[gg][kc] = (i64)wx8[(long long)((gg * 16 + wv) * 4 + kc) * 64 + lane];
#pragma unroll
  for (int kc = 0; kc < 8; kc++) {
    whhZ[kc] = (i64)wh8[(long long)((16 + wv) * 8 + kc) * 64 + lane];
    whhN[kc] = (i64)wh8[(long long)((32 + wv) * 8 + kc) * 64 + lane];
  }

  const int col = wv * 16 + cl;
  const float bhh0 = b_hh[col], bhh1 = b_hh[256 + col], bhh2 = b_hh[512 + col];
  const bool rowok = (rq < 4);
  const bool vwave = (wv < 7);
  const int vcol = col;
  const bool vact = vwave && (vcol < V_);
  const bool vld = vact && rowok;
  const float bh = vact ? b_hist[vcol] : 0.f;
  const float cw0 = conv_w[0], cw1 = conv_w[1], cb = conv_b[0];

  const u16* gamp = wsu + WS_GAMMA / 2;
  const u16* x16p = wsu + WS_X16 / 2;
  const u16* xu16p = wsu + WS_XUS16 / 2;
  const u16* xrpp = wsu + WS_XRPRE / 2;
  const u8* m8p = ws8 + WS_M8;
  int lane_p = ((quarter + (rq >> 2)) * 16 + cl) & 63;
  const u8* gimp = ws8 + WS_GIM8 + (((long long)cc * 48 + wv) * 64 + lane_p) * 4;

  u32 gaidx = BH_ + (u32)(b0 + rq) * H_ + col;
  u32 xidx = (u32)(b0 + rq) * 100 + vcol;
  u32 xuidx = (u32)(b0 + rq) * 99 + vcol;
  u32 midx = (u32)(b0 + rq) * 104 + vcol;
  u32 gidx = (u32)(b0 + rq) * TV_ + vcol;

  float hpr[4] = {0.f, 0.f, 0.f, 0.f};
  float loss_acc = 0.f;
  constexpr float inv128 = 1.f / 128.f;
  constexpr float inv64 = 1.f / 64.f;
  const f32x4 z4 = {0.f, 0.f, 0.f, 0.f};
  __syncthreads();

  for (int t = 0; t < T_; t++) {
    // ---- step-top: issue all global loads ----
    u32 gimw0, gimw1, gimw2;
    {
      const u32* gp = reinterpret_cast<const u32*>(gimp + (long long)t * 393216);
      gimw0 = gp[0]; gimw1 = gp[1024]; gimw2 = gp[2048];
    }
    u16 ga[4] = {0, 0, 0, 0};
    if (rowok && t + 1 < T_) {
#pragma unroll
      for (int j = 0; j < 4; j++) ga[j] = gamp[gaidx + (u32)j * H_];
    }
    gaidx += BH_;
    u16 cx16[4] = {0, 0, 0, 0}, cxu[4] = {0, 0, 0, 0}, cxr[4] = {0, 0, 0, 0};
    u8 cm8[4] = {0, 0, 0, 0};
    if (vld) {
#pragma unroll
      for (int j = 0; j < 4; j++) {
        cx16[j] = x16p[xidx + (u32)j * 100];
        cxu[j]  = xu16p[xuidx + (u32)j * 99];
        cxr[j]  = xrpp[xuidx + (u32)j * 99];
        cm8[j]  = m8p[midx + (u32)j * 104];
      }
    }
    xidx += B_ * 100; xuidx += B_ * 99; midx += B_ * 104;
    const float msv = msum[t];

    // ---- P1: gh chains + x_h ----
    f32x4 accR = z4, accZ = z4, accNh = z4, accXh = z4;
#pragma unroll
    for (int kc = 0; kc < 8; kc++) {
      const i64 a = *reinterpret_cast<const i64*>(&hp8_s[cl * 272 + kc * 32 + kr8]);
      const i64 br = *reinterpret_cast<const i64*>(&whhR_l[(wv * 8 + kc) * 512 + lane * 8]);
      accR  = mfma8(a, br, accR);
      accZ  = mfma8(a, whhZ[kc], accZ);
      accNh = mfma8(a, whhN[kc], accNh);
      if (vwave) {
        const i64 bw = *reinterpret_cast<const i64*>(&whist8_l[(wv * 8 + kc) * 512 + lane * 8]);
        accXh = mfma8(a, bw, accXh);
      }
    }
    if (vld) {
#pragma unroll
      for (int j = 0; j < 4; j++) {
        const float xhv = accXh[j] * inv128 + bh;
        const float ev = cm8[j] ? 0.f : xhv;
        e8_s[(rq + j) * 144 + vcol] = (u8)cvtfp8(ev * 8.f);
      }
    }
    __syncthreads();

    // ---- P2: xr, x_comb, loss, x_imp, xrs ----
    if (vwave) {
      f32x4 acc = z4;
#pragma unroll
      for (int kc = 0; kc < 4; kc++) {
        const i64 a = *reinterpret_cast<const i64*>(&e8_s[cl * 144 + kc * 32 + kr8]);
        const i64 b = *reinterpret_cast<const i64*>(&wr8_l[(wv * 4 + kc) * 512 + lane * 8]);
        acc = mfma8(a, b, acc);
      }
      if (vld) {
        const float inv_ms = 1.f / (msv + 1e-5f);
        float ls = 0.f;
#pragma unroll
        for (int j = 0; j < 4; j++) {
          const float xrv = acc[j] * inv128 + cvt_f32(cxr[j]);
          const float xc = cw0 * cvt_f32(cxu[j]) + cw1 * xrv + cb;
          const float xj = cvt_f32(cx16[j]);
          const bool mj = cm8[j] != 0;
          const float ximp = mj ? xj : xc;
          ls += mj ? fabsf(xj - xc) : 0.f;
          const u32 gj = gidx + (u32)j * TV_;
          out[XIMP_O + gj] = ximp;
          out[XRS_O + gj] = xrv;
          xi8_s[(rq + j) * 144 + vcol] = (u8)cvtfp8(ximp * 8.f);
        }
        loss_acc += ls * inv_ms;
      }
    }
    gidx += V_;
    __syncthreads();

    // ---- P3: gi x-part + GRU update (+ fused gamma[t+1]) ----
    f32x4 accNx = z4;
#pragma unroll
    for (int kc = 0; kc < 4; kc++) {
      const i64 a = *reinterpret_cast<const i64*>(&xi8_s[cl * 144 + kc * 32 + kr8]);
      accR  = mfma8(a, wihx_r[0][kc], accR);
      accZ  = mfma8(a, wihx_r[1][kc], accZ);
      accNx = mfma8(a, wihx_r[2][kc], accNx);
    }
    const f32x4 gimR = dec8x4(gimw0);
    const f32x4 gimZ = dec8x4(gimw1);
    const f32x4 gimN = dec8x4(gimw2);
#pragma unroll
    for (int j = 0; j < 4; j++) {
      const float rr = sigm(accR[j] * inv128 + gimR[j] * inv64 + bhh0);
      const float zz = sigm(accZ[j] * inv128 + gimZ[j] * inv64 + bhh1);
      const float gin = accNx[j] * inv128 + gimN[j] * inv64;
      const float ghn = accNh[j] * inv128 + bhh2;
      const float nn = tanhx(gin + rr * ghn);
      const float hn = (1.f - zz) * nn + zz * hpr[j];
      if (t + 1 < T_) {
        const float hpnew = hn * cvt_f32(ga[j]);
        hpr[j] = hpnew;
        if (rowok) hp8_s[(rq + j) * 272 + col] = (u8)cvtfp8(hpnew * 8.f);
      } else {
        if (rowok) hf_s[rq + j][col] = hn;
      }
    }
    __syncthreads();
  }

  // ---- epilogue ----
  if (tid < 4) {
    float acc = 0.f;
    for (int k = 0; k < H_; k++) acc += hf_s[tid][k] * W_fc[k];
    const float yv = acc + b_fc[0];
    out[YOUT_O + b0 + tid] = yv;
    out[YSC_O + b0 + tid] = 1.f / (1.f + __expf(-yv));
  }
  red_s[tid] = loss_acc;
  __syncthreads();
  for (int s = 512; s; s >>= 1) {
    if (tid < s) red_s[tid] += red_s[tid + s];
    __syncthreads();
  }
  if (tid == 0) {
    float* lp = reinterpret_cast<float*>(reinterpret_cast<char*>(wsu) + WS_LOSSP);
    lp[blockIdx.x] = red_s[0];
  }
}

// ---------------- K3: deterministic loss reduction ----------------
__global__ void k3_loss(const float* __restrict__ lossp, float* __restrict__ out) {
  if (threadIdx.x == 0) {
    float s = 0.f;
    for (int i = 0; i < 128; i++) s += lossp[i];
    out[LOSS_O] = s;
  }
}

extern "C" void kernel_launch(void* const* d_in, const int* in_sizes, int n_in,
                              void* d_out, int out_size, void* d_ws, size_t ws_size,
                              hipStream_t stream) {
  (void)in_sizes; (void)n_in; (void)out_size; (void)ws_size;
  const float* x      = (const float*)d_in[0];
  const float* xhat   = (const float*)d_in[1];
  const float* u      = (const float*)d_in[2];
  const float* m      = (const float*)d_in[3];
  const float* d      = (const float*)d_in[4];
  const float* W_td   = (const float*)d_in[6];
  const float* b_td   = (const float*)d_in[7];
  const float* W_hist = (const float*)d_in[8];
  const float* b_hist = (const float*)d_in[9];
  const float* W_v    = (const float*)d_in[10];
  const float* b_v    = (const float*)d_in[11];
  const float* W_r    = (const float*)d_in[12];
  const float* b_r    = (const float*)d_in[13];
  const float* W_u    = (const float*)d_in[14];
  const float* b_u    = (const float*)d_in[15];
  const float* conv_w = (const float*)d_in[16];
  const float* conv_b = (const float*)d_in[17];
  const float* W_ih   = (const float*)d_in[18];
  const float* b_ih   = (const float*)d_in[19];
  const float* W_hh   = (const float*)d_in[20];
  const float* b_hh   = (const float*)d_in[21];
  const float* W_fc   = (const float*)d_in[22];
  const float* b_fc   = (const float*)d_in[23];
  float* out = (float*)d_out;
  u16* wsu = (u16*)d_ws;
  float* msum = (float*)d_ws;
  const float* lossp = (const float*)((char*)d_ws + WS_LOSSP);

  hipLaunchKernelGGL(k0_all, dim3(251), dim3(256), 0, stream,
                     W_td, W_u, W_v, W_r, W_ih, W_hh, W_hist, msum, wsu);
  hipLaunchKernelGGL(k2_pre, dim3(1600), dim3(256), 0, stream,
                     x, xhat, u, m, d, b_td, b_u, b_v, b_r, b_ih, msum, out, wsu);
  hipLaunchKernelGGL(k_seq, dim3(128), dim3(1024), 0, stream,
                     b_hist, b_hh, conv_w, conv_b, W_fc, b_fc, msum, out, wsu);
  hipLaunchKernelGGL(k3_loss, dim3(1), dim3(64), 0, stream, lossp, out);
}